// Round 2
// baseline (5846.866 us; speedup 1.0000x reference)
//
#include <hip/hip_runtime.h>
#include <math.h>

#define B_N 256
#define V_N 6890
#define J_N 24
#define KPF 207
#define KE  218
#define NCOL (V_N*3)   // 20670

__device__ __constant__ int c_par[24] = {-1,0,0,0,1,2,3,4,5,6,7,8,9,9,9,12,13,14,16,17,18,19,20,21};

// ws layout (floats)
#define WS_PF   0
#define WS_A    (WS_PF + B_N*KE)                 // 55808
#define WS_EXT  (WS_A + B_N*J_N*12)              // 129536
#define WS_JS   (WS_EXT + 11*NCOL)               // 356906
#define WS_JT0  (WS_JS + J_N*30)                 // 357626
#define WS_PART (WS_JT0 + J_N*3)                 // 357698  (96*33 = 3168)

// ---------------- stage 0a: partial joint-regressor contraction ----------------
__global__ __launch_bounds__(256) void k_jreg(const float* __restrict__ Jreg,
        const float* __restrict__ vt, const float* __restrict__ sd,
        float* __restrict__ part)
{
    int j = blockIdx.x;
    int c = blockIdx.y;
    int tid = threadIdx.x;
    int v0 = c * 1723;
    int v1 = v0 + 1723; if (v1 > V_N) v1 = V_N;

    float acc[33];
    #pragma unroll
    for (int i = 0; i < 33; ++i) acc[i] = 0.f;

    for (int v = v0 + tid; v < v1; v += 256) {
        float r = Jreg[j*V_N + v];
        const float* s = sd + v*30;
        #pragma unroll
        for (int i = 0; i < 30; ++i) acc[i] += r * s[i];
        #pragma unroll
        for (int k = 0; k < 3; ++k) acc[30+k] += r * vt[v*3+k];
    }
    #pragma unroll
    for (int i = 0; i < 33; ++i) {
        #pragma unroll
        for (int off = 32; off > 0; off >>= 1)
            acc[i] += __shfl_down(acc[i], off, 64);
    }
    __shared__ float red[4][33];
    int wave = tid >> 6, lane = tid & 63;
    if (lane == 0) {
        #pragma unroll
        for (int i = 0; i < 33; ++i) red[wave][i] = acc[i];
    }
    __syncthreads();
    if (tid < 33) {
        float s = red[0][tid] + red[1][tid] + red[2][tid] + red[3][tid];
        part[(j*4 + c)*33 + tid] = s;
    }
}

__global__ __launch_bounds__(64) void k_jred(const float* __restrict__ part,
        float* __restrict__ JS, float* __restrict__ Jt0)
{
    int j = blockIdx.x;
    int tid = threadIdx.x;
    if (tid < 33) {
        float s = 0.f;
        for (int c = 0; c < 4; ++c) s += part[(j*4 + c)*33 + tid];
        if (tid < 30) JS[j*30 + tid] = s;
        else          Jt0[j*3 + (tid - 30)] = s;
    }
}

// ---------------- stage 0b: build extended "posedirs" rows 207..217 ----------------
__global__ __launch_bounds__(256) void k_ext(const float* __restrict__ sd,
        const float* __restrict__ vt, float* __restrict__ EXT)
{
    int idx = blockIdx.x*256 + threadIdx.x;
    if (idx >= NCOL) return;
    int v = idx / 3, k = idx - v*3;
    #pragma unroll
    for (int l = 0; l < 10; ++l) EXT[l*NCOL + idx] = sd[v*30 + k*10 + l];
    EXT[10*NCOL + idx] = vt[idx];
}

// ---------------- stage 1: per-batch Rodrigues + kinematic chain ----------------
__global__ __launch_bounds__(64) void k_batch(const float* __restrict__ pose,
        const float* __restrict__ betas, const float* __restrict__ JS,
        const float* __restrict__ Jt0, float* __restrict__ PF,
        float* __restrict__ A, float* __restrict__ outJ)
{
    int b = blockIdx.x;
    int lane = threadIdx.x;
    __shared__ float sR[24][9];
    __shared__ float sJ[24][3];
    __shared__ float sG[24][12];

    if (lane < 24) {
        float R[9];
        if (lane < 22) {
            float p0 = pose[b*72 + lane*3 + 0];
            float p1 = pose[b*72 + lane*3 + 1];
            float p2 = pose[b*72 + lane*3 + 2];
            float a0 = p0 + 1e-8f, a1 = p1 + 1e-8f, a2 = p2 + 1e-8f;
            float angle = sqrtf(a0*a0 + a1*a1 + a2*a2);
            float inv = 1.f / angle;
            float rx = p0*inv, ry = p1*inv, rz = p2*inv;
            float cc = cosf(angle), ss = sinf(angle), ic = 1.f - cc;
            R[0] = 1.f - ic*(ry*ry + rz*rz);
            R[1] = -ss*rz + ic*rx*ry;
            R[2] =  ss*ry + ic*rx*rz;
            R[3] =  ss*rz + ic*rx*ry;
            R[4] = 1.f - ic*(rx*rx + rz*rz);
            R[5] = -ss*rx + ic*ry*rz;
            R[6] = -ss*ry + ic*rx*rz;
            R[7] =  ss*rx + ic*ry*rz;
            R[8] = 1.f - ic*(rx*rx + ry*ry);
        } else {
            R[0]=1.f;R[1]=0.f;R[2]=0.f;R[3]=0.f;R[4]=1.f;R[5]=0.f;R[6]=0.f;R[7]=0.f;R[8]=1.f;
        }
        #pragma unroll
        for (int e = 0; e < 9; ++e) sR[lane][e] = R[e];
    }
    __syncthreads();
    for (int idx = lane; idx < 72; idx += 64) {
        float s = Jt0[idx];
        #pragma unroll
        for (int l = 0; l < 10; ++l) s += betas[b*10+l] * JS[idx*10 + l];
        sJ[idx/3][idx%3] = s;
    }
    __syncthreads();
    for (int idx = lane; idx < KPF; idx += 64) {
        int jj = 1 + idx/9, e = idx - (idx/9)*9;
        float id = (e==0 || e==4 || e==8) ? 1.f : 0.f;
        PF[b*KE + idx] = sR[jj][e] - id;
    }
    if (lane < 10) PF[b*KE + KPF + lane] = betas[b*10 + lane];
    if (lane == 0) PF[b*KE + 217] = 1.f;

    if (lane == 0) {
        #pragma unroll
        for (int r = 0; r < 3; ++r) {
            sG[0][r*4+0] = sR[0][r*3+0];
            sG[0][r*4+1] = sR[0][r*3+1];
            sG[0][r*4+2] = sR[0][r*3+2];
            sG[0][r*4+3] = sJ[0][r];
        }
        for (int i = 1; i < 24; ++i) {
            int p = c_par[i];
            float rel0 = sJ[i][0]-sJ[p][0], rel1 = sJ[i][1]-sJ[p][1], rel2 = sJ[i][2]-sJ[p][2];
            for (int r = 0; r < 3; ++r) {
                float g0 = sG[p][r*4+0], g1 = sG[p][r*4+1], g2 = sG[p][r*4+2], g3 = sG[p][r*4+3];
                sG[i][r*4+0] = g0*sR[i][0] + g1*sR[i][3] + g2*sR[i][6];
                sG[i][r*4+1] = g0*sR[i][1] + g1*sR[i][4] + g2*sR[i][7];
                sG[i][r*4+2] = g0*sR[i][2] + g1*sR[i][5] + g2*sR[i][8];
                sG[i][r*4+3] = g0*rel0 + g1*rel1 + g2*rel2 + g3;
            }
        }
    }
    __syncthreads();
    if (lane < 24) {
        int i = lane;
        #pragma unroll
        for (int r = 0; r < 3; ++r) {
            float g0 = sG[i][r*4+0], g1 = sG[i][r*4+1], g2 = sG[i][r*4+2], g3 = sG[i][r*4+3];
            outJ[b*72 + i*3 + r] = g3;
            float t = g3 - (g0*sJ[i][0] + g1*sJ[i][1] + g2*sJ[i][2]);
            A[(b*24+i)*12 + r*4+0] = g0;
            A[(b*24+i)*12 + r*4+1] = g1;
            A[(b*24+i)*12 + r*4+2] = g2;
            A[(b*24+i)*12 + r*4+3] = t;
        }
    }
}

// ---------------- stage 2: fused (v_posed GEMM + skinning) ----------------
// block = 256 thr = 4 waves. Block tile: 64 verts x 16 batches.
// Main loop: thread = (vert = lane, 4 batches = wave*4+k). Per K-row:
//   1 conflict-free ds_read_b128 (vert xyz) + 1 broadcast ds_read_b128 (4 PF) -> 12 FMA.
// Epilogue: per-batch T[12] (k outer) so only 12 T floats live -> no scratch spill.
__global__ __launch_bounds__(256) void k_verts(
        const float* __restrict__ posedirs, const float* __restrict__ EXT,
        const float* __restrict__ PF, const float* __restrict__ A,
        const float* __restrict__ W, float* __restrict__ out)
{
    constexpr int KT = 28;
    __shared__ __align__(16) float sPFt[KE][16];       // 13952 B
    __shared__ __align__(16) float sW[64][25];         //  6400 B
    __shared__ __align__(16) float sPD[KT*64*4];       // 28672 B (reused as sA in epilogue)
    float* sA = sPD;                                    // 16*296 = 4736 floats needed

    int tid  = threadIdx.x;
    int wave = tid >> 6, lane = tid & 63;
    int v0 = blockIdx.x * 64;
    int b0 = blockIdx.y * 16;

    for (int idx = tid; idx < 16*KE; idx += 256) {
        int bl = idx / KE, r = idx - bl*KE;
        sPFt[r][bl] = PF[(b0+bl)*KE + r];
    }
    for (int idx = tid; idx < 64*24; idx += 256) {
        int vv = idx / 24, j = idx - vv*24;
        int vg = v0 + vv;
        sW[vv][j] = (vg < V_N) ? W[vg*24 + j] : 0.f;
    }
    __syncthreads();

    float acc[4][3];
    #pragma unroll
    for (int k = 0; k < 4; ++k) { acc[k][0]=0.f; acc[k][1]=0.f; acc[k][2]=0.f; }

    for (int rt = 0; rt < KE; rt += KT) {
        int rows = KE - rt; if (rows > KT) rows = KT;
        for (int idx = tid; idx < rows*192; idx += 256) {
            int rr = idx / 192, c = idx - rr*192;
            int r = rt + rr;
            int col = v0*3 + c; if (col >= NCOL) col = NCOL - 1;
            const float* src = (r < KPF) ? (posedirs + (size_t)r*NCOL)
                                         : (EXT + (size_t)(r-KPF)*NCOL);
            int vv = c / 3;
            sPD[(rr*64 + vv)*4 + (c - vv*3)] = src[col];
        }
        __syncthreads();
        for (int rr = 0; rr < rows; ++rr) {
            const float4 c4 = *reinterpret_cast<const float4*>(&sPD[(rr*64 + lane)*4]);
            const float4 p4 = *reinterpret_cast<const float4*>(&sPFt[rt+rr][wave*4]);
            acc[0][0] += p4.x*c4.x; acc[0][1] += p4.x*c4.y; acc[0][2] += p4.x*c4.z;
            acc[1][0] += p4.y*c4.x; acc[1][1] += p4.y*c4.y; acc[1][2] += p4.y*c4.z;
            acc[2][0] += p4.z*c4.x; acc[2][1] += p4.z*c4.y; acc[2][2] += p4.z*c4.z;
            acc[3][0] += p4.w*c4.x; acc[3][1] += p4.w*c4.y; acc[3][2] += p4.w*c4.z;
        }
        __syncthreads();
    }

    // epilogue: stage A (16 batches x 24 joints x 12) into reused LDS, stride 296
    for (int idx = tid; idx < 16*288; idx += 256) {
        int bl = idx / 288, e = idx - bl*288;
        sA[bl*296 + e] = A[(size_t)(b0+bl)*288 + e];
    }
    __syncthreads();

    // per-vertex lbs weights (vert = lane), 24 regs, statically indexed
    float wv[24];
    #pragma unroll
    for (int j = 0; j < 24; ++j) wv[j] = sW[lane][j];

    int v = v0 + lane;
    #pragma unroll
    for (int k = 0; k < 4; ++k) {
        int bb = wave*4 + k;
        const float* Ab = sA + bb*296;
        float T[12];
        #pragma unroll
        for (int e = 0; e < 12; ++e) T[e] = 0.f;
        #pragma unroll 4
        for (int j = 0; j < 24; ++j) {
            float4 a0 = *reinterpret_cast<const float4*>(Ab + j*12 + 0);
            float4 a1 = *reinterpret_cast<const float4*>(Ab + j*12 + 4);
            float4 a2 = *reinterpret_cast<const float4*>(Ab + j*12 + 8);
            float w = wv[j];
            T[0] += w*a0.x; T[1] += w*a0.y; T[2]  += w*a0.z; T[3]  += w*a0.w;
            T[4] += w*a1.x; T[5] += w*a1.y; T[6]  += w*a1.z; T[7]  += w*a1.w;
            T[8] += w*a2.x; T[9] += w*a2.y; T[10] += w*a2.z; T[11] += w*a2.w;
        }
        if (v < V_N) {
            float x = acc[k][0], y = acc[k][1], z = acc[k][2];
            size_t o = (size_t)(b0 + bb)*NCOL + (size_t)v*3;
            out[o+0] = T[0]*x + T[1]*y + T[2]*z  + T[3];
            out[o+1] = T[4]*x + T[5]*y + T[6]*z  + T[7];
            out[o+2] = T[8]*x + T[9]*y + T[10]*z + T[11];
        }
    }
}

extern "C" void kernel_launch(void* const* d_in, const int* in_sizes, int n_in,
                              void* d_out, int out_size, void* d_ws, size_t ws_size,
                              hipStream_t stream)
{
    const float* betas      = (const float*)d_in[0];
    const float* pose       = (const float*)d_in[1];
    const float* v_template = (const float*)d_in[2];
    const float* shapedirs  = (const float*)d_in[3];
    const float* posedirs   = (const float*)d_in[4];
    const float* Jreg       = (const float*)d_in[5];
    const float* lbs        = (const float*)d_in[6];

    float* ws   = (float*)d_ws;
    float* PF   = ws + WS_PF;
    float* A    = ws + WS_A;
    float* EXT  = ws + WS_EXT;
    float* JS   = ws + WS_JS;
    float* Jt0  = ws + WS_JT0;
    float* part = ws + WS_PART;

    float* verts = (float*)d_out;
    float* outJ  = verts + (size_t)B_N*V_N*3;

    hipLaunchKernelGGL(k_jreg, dim3(24,4), dim3(256), 0, stream, Jreg, v_template, shapedirs, part);
    hipLaunchKernelGGL(k_ext, dim3((NCOL+255)/256), dim3(256), 0, stream, shapedirs, v_template, EXT);
    hipLaunchKernelGGL(k_jred, dim3(24), dim3(64), 0, stream, part, JS, Jt0);
    hipLaunchKernelGGL(k_batch, dim3(256), dim3(64), 0, stream, pose, betas, JS, Jt0, PF, A, outJ);
    hipLaunchKernelGGL(k_verts, dim3((V_N+63)/64, 16), dim3(256), 0, stream, posedirs, EXT, PF, A, lbs, verts);
}

// Round 3
// 205.304 us; speedup vs baseline: 28.4790x; 28.4790x over previous
//
#include <hip/hip_runtime.h>
#include <math.h>

#define B_N 256
#define V_N 6890
#define J_N 24
#define KPF 207
#define KE  218
#define NCOL (V_N*3)   // 20670

__device__ __constant__ int c_par[24] = {-1,0,0,0,1,2,3,4,5,6,7,8,9,9,9,12,13,14,16,17,18,19,20,21};

// ws layout (floats)
#define WS_PF   0
#define WS_A    (WS_PF + B_N*KE)                 // 55808
#define WS_EXT  (WS_A + B_N*J_N*12)              // 129536
#define WS_JS   (WS_EXT + 11*NCOL)               // 356906
#define WS_JT0  (WS_JS + J_N*30)                 // 357626
#define WS_PART (WS_JT0 + J_N*3)                 // 357698  (96*33 = 3168)

// ---------------- stage 0a: partial joint-regressor contraction ----------------
__global__ __launch_bounds__(256) void k_jreg(const float* __restrict__ Jreg,
        const float* __restrict__ vt, const float* __restrict__ sd,
        float* __restrict__ part)
{
    int j = blockIdx.x;
    int c = blockIdx.y;
    int tid = threadIdx.x;
    int v0 = c * 1723;
    int v1 = v0 + 1723; if (v1 > V_N) v1 = V_N;

    float acc[33];
    #pragma unroll
    for (int i = 0; i < 33; ++i) acc[i] = 0.f;

    for (int v = v0 + tid; v < v1; v += 256) {
        float r = Jreg[j*V_N + v];
        const float* s = sd + v*30;
        #pragma unroll
        for (int i = 0; i < 30; ++i) acc[i] += r * s[i];
        #pragma unroll
        for (int k = 0; k < 3; ++k) acc[30+k] += r * vt[v*3+k];
    }
    #pragma unroll
    for (int i = 0; i < 33; ++i) {
        #pragma unroll
        for (int off = 32; off > 0; off >>= 1)
            acc[i] += __shfl_down(acc[i], off, 64);
    }
    __shared__ float red[4][33];
    int wave = tid >> 6, lane = tid & 63;
    if (lane == 0) {
        #pragma unroll
        for (int i = 0; i < 33; ++i) red[wave][i] = acc[i];
    }
    __syncthreads();
    if (tid < 33) {
        float s = red[0][tid] + red[1][tid] + red[2][tid] + red[3][tid];
        part[(j*4 + c)*33 + tid] = s;
    }
}

__global__ __launch_bounds__(64) void k_jred(const float* __restrict__ part,
        float* __restrict__ JS, float* __restrict__ Jt0)
{
    int j = blockIdx.x;
    int tid = threadIdx.x;
    if (tid < 33) {
        float s = 0.f;
        for (int c = 0; c < 4; ++c) s += part[(j*4 + c)*33 + tid];
        if (tid < 30) JS[j*30 + tid] = s;
        else          Jt0[j*3 + (tid - 30)] = s;
    }
}

// ---------------- stage 0b: build extended "posedirs" rows 207..217 ----------------
__global__ __launch_bounds__(256) void k_ext(const float* __restrict__ sd,
        const float* __restrict__ vt, float* __restrict__ EXT)
{
    int idx = blockIdx.x*256 + threadIdx.x;
    if (idx >= NCOL) return;
    int v = idx / 3, k = idx - v*3;
    #pragma unroll
    for (int l = 0; l < 10; ++l) EXT[l*NCOL + idx] = sd[v*30 + k*10 + l];
    EXT[10*NCOL + idx] = vt[idx];
}

// ---------------- stage 1: per-batch Rodrigues + kinematic chain ----------------
__global__ __launch_bounds__(64) void k_batch(const float* __restrict__ pose,
        const float* __restrict__ betas, const float* __restrict__ JS,
        const float* __restrict__ Jt0, float* __restrict__ PF,
        float* __restrict__ A, float* __restrict__ outJ)
{
    int b = blockIdx.x;
    int lane = threadIdx.x;
    __shared__ float sR[24][9];
    __shared__ float sJ[24][3];
    __shared__ float sG[24][12];

    if (lane < 24) {
        float R[9];
        if (lane < 22) {
            float p0 = pose[b*72 + lane*3 + 0];
            float p1 = pose[b*72 + lane*3 + 1];
            float p2 = pose[b*72 + lane*3 + 2];
            float a0 = p0 + 1e-8f, a1 = p1 + 1e-8f, a2 = p2 + 1e-8f;
            float angle = sqrtf(a0*a0 + a1*a1 + a2*a2);
            float inv = 1.f / angle;
            float rx = p0*inv, ry = p1*inv, rz = p2*inv;
            float cc = cosf(angle), ss = sinf(angle), ic = 1.f - cc;
            R[0] = 1.f - ic*(ry*ry + rz*rz);
            R[1] = -ss*rz + ic*rx*ry;
            R[2] =  ss*ry + ic*rx*rz;
            R[3] =  ss*rz + ic*rx*ry;
            R[4] = 1.f - ic*(rx*rx + rz*rz);
            R[5] = -ss*rx + ic*ry*rz;
            R[6] = -ss*ry + ic*rx*rz;
            R[7] =  ss*rx + ic*ry*rz;
            R[8] = 1.f - ic*(rx*rx + ry*ry);
        } else {
            R[0]=1.f;R[1]=0.f;R[2]=0.f;R[3]=0.f;R[4]=1.f;R[5]=0.f;R[6]=0.f;R[7]=0.f;R[8]=1.f;
        }
        #pragma unroll
        for (int e = 0; e < 9; ++e) sR[lane][e] = R[e];
    }
    __syncthreads();
    for (int idx = lane; idx < 72; idx += 64) {
        float s = Jt0[idx];
        #pragma unroll
        for (int l = 0; l < 10; ++l) s += betas[b*10+l] * JS[idx*10 + l];
        sJ[idx/3][idx%3] = s;
    }
    __syncthreads();
    for (int idx = lane; idx < KPF; idx += 64) {
        int jj = 1 + idx/9, e = idx - (idx/9)*9;
        float id = (e==0 || e==4 || e==8) ? 1.f : 0.f;
        PF[b*KE + idx] = sR[jj][e] - id;
    }
    if (lane < 10) PF[b*KE + KPF + lane] = betas[b*10 + lane];
    if (lane == 0) PF[b*KE + 217] = 1.f;

    if (lane == 0) {
        #pragma unroll
        for (int r = 0; r < 3; ++r) {
            sG[0][r*4+0] = sR[0][r*3+0];
            sG[0][r*4+1] = sR[0][r*3+1];
            sG[0][r*4+2] = sR[0][r*3+2];
            sG[0][r*4+3] = sJ[0][r];
        }
        for (int i = 1; i < 24; ++i) {
            int p = c_par[i];
            float rel0 = sJ[i][0]-sJ[p][0], rel1 = sJ[i][1]-sJ[p][1], rel2 = sJ[i][2]-sJ[p][2];
            for (int r = 0; r < 3; ++r) {
                float g0 = sG[p][r*4+0], g1 = sG[p][r*4+1], g2 = sG[p][r*4+2], g3 = sG[p][r*4+3];
                sG[i][r*4+0] = g0*sR[i][0] + g1*sR[i][3] + g2*sR[i][6];
                sG[i][r*4+1] = g0*sR[i][1] + g1*sR[i][4] + g2*sR[i][7];
                sG[i][r*4+2] = g0*sR[i][2] + g1*sR[i][5] + g2*sR[i][8];
                sG[i][r*4+3] = g0*rel0 + g1*rel1 + g2*rel2 + g3;
            }
        }
    }
    __syncthreads();
    if (lane < 24) {
        int i = lane;
        #pragma unroll
        for (int r = 0; r < 3; ++r) {
            float g0 = sG[i][r*4+0], g1 = sG[i][r*4+1], g2 = sG[i][r*4+2], g3 = sG[i][r*4+3];
            outJ[b*72 + i*3 + r] = g3;
            float t = g3 - (g0*sJ[i][0] + g1*sJ[i][1] + g2*sJ[i][2]);
            A[(b*24+i)*12 + r*4+0] = g0;
            A[(b*24+i)*12 + r*4+1] = g1;
            A[(b*24+i)*12 + r*4+2] = g2;
            A[(b*24+i)*12 + r*4+3] = t;
        }
    }
}

// ---------------- stage 2a: v_posed GEMM only ----------------
// block = 256 thr. Tile: 64 verts x 16 batches. thread = (vert=lane, 4 batches).
// Writes v_posed into the verts region of d_out (transformed in place by k_skin).
__global__ __launch_bounds__(256) void k_gemm(
        const float* __restrict__ posedirs, const float* __restrict__ EXT,
        const float* __restrict__ PF, float* __restrict__ vout)
{
    constexpr int KT = 28;
    __shared__ __align__(16) float sPFt[KE][16];       // 13952 B
    __shared__ __align__(16) float sPD[KT*64*4];       // 21504 B

    int tid  = threadIdx.x;
    int wave = tid >> 6, lane = tid & 63;
    int v0 = blockIdx.x * 64;
    int b0 = blockIdx.y * 16;

    // stage PF^T: bl fast in tid -> conflict-free LDS writes
    #pragma unroll 1
    for (int idx = tid; idx < 16*KE; idx += 256) {
        int bl = idx & 15, r = idx >> 4;
        sPFt[r][bl] = PF[(b0+bl)*KE + r];
    }
    __syncthreads();

    float acc[4][3];
    #pragma unroll
    for (int k = 0; k < 4; ++k) { acc[k][0]=0.f; acc[k][1]=0.f; acc[k][2]=0.f; }

    #pragma unroll 1
    for (int rt = 0; rt < KE; rt += KT) {
        int rows = KE - rt; if (rows > KT) rows = KT;
        #pragma unroll 1
        for (int idx = tid; idx < rows*192; idx += 256) {
            int rr = idx / 192, c = idx - rr*192;
            int r = rt + rr;
            int col = v0*3 + c; if (col >= NCOL) col = NCOL - 1;
            const float* src = (r < KPF) ? (posedirs + (size_t)r*NCOL)
                                         : (EXT + (size_t)(r-KPF)*NCOL);
            int vv = c / 3;
            sPD[(rr*64 + vv)*4 + (c - vv*3)] = src[col];
        }
        __syncthreads();
        #pragma unroll 2
        for (int rr = 0; rr < rows; ++rr) {
            const float4 c4 = *reinterpret_cast<const float4*>(&sPD[(rr*64 + lane)*4]);
            const float4 p4 = *reinterpret_cast<const float4*>(&sPFt[rt+rr][wave*4]);
            acc[0][0] += p4.x*c4.x; acc[0][1] += p4.x*c4.y; acc[0][2] += p4.x*c4.z;
            acc[1][0] += p4.y*c4.x; acc[1][1] += p4.y*c4.y; acc[1][2] += p4.y*c4.z;
            acc[2][0] += p4.z*c4.x; acc[2][1] += p4.z*c4.y; acc[2][2] += p4.z*c4.z;
            acc[3][0] += p4.w*c4.x; acc[3][1] += p4.w*c4.y; acc[3][2] += p4.w*c4.z;
        }
        __syncthreads();
    }

    int v = v0 + lane;
    if (v < V_N) {
        #pragma unroll
        for (int k = 0; k < 4; ++k) {
            size_t o = (size_t)(b0 + wave*4 + k)*NCOL + (size_t)v*3;
            vout[o+0] = acc[k][0];
            vout[o+1] = acc[k][1];
            vout[o+2] = acc[k][2];
        }
    }
}

// ---------------- stage 2b: skinning (in-place on verts) ----------------
// thread = (vert = lane, 4 batches). j-loop fully unrolled: all arrays static.
__global__ __launch_bounds__(256) void k_skin(
        const float* __restrict__ A, const float* __restrict__ W,
        float* __restrict__ verts)
{
    __shared__ __align__(16) float sA[16*288];          // 18432 B
    __shared__ float sW[64][25];                        //  6400 B

    int tid  = threadIdx.x;
    int wave = tid >> 6, lane = tid & 63;
    int v0 = blockIdx.x * 64;
    int b0 = blockIdx.y * 16;

    #pragma unroll 1
    for (int idx = tid; idx < 16*288; idx += 256)
        sA[idx] = A[(size_t)b0*288 + idx];
    #pragma unroll 1
    for (int idx = tid; idx < 64*24; idx += 256) {
        int vv = idx / 24, j = idx - vv*24;
        int vg = v0 + vv;
        sW[vv][j] = (vg < V_N) ? W[vg*24 + j] : 0.f;
    }
    __syncthreads();

    int v = v0 + lane;
    if (v >= V_N) return;

    #pragma unroll 1
    for (int k = 0; k < 4; ++k) {
        int bb = wave*4 + k;
        size_t o = (size_t)(b0 + bb)*NCOL + (size_t)v*3;
        float x = verts[o+0], y = verts[o+1], z = verts[o+2];
        const float* Ab = sA + bb*288;
        float T[12];
        #pragma unroll
        for (int e = 0; e < 12; ++e) T[e] = 0.f;
        #pragma unroll
        for (int j = 0; j < 24; ++j) {
            float w = sW[lane][j];
            float4 a0 = *reinterpret_cast<const float4*>(Ab + j*12 + 0);
            float4 a1 = *reinterpret_cast<const float4*>(Ab + j*12 + 4);
            float4 a2 = *reinterpret_cast<const float4*>(Ab + j*12 + 8);
            T[0] += w*a0.x; T[1] += w*a0.y; T[2]  += w*a0.z; T[3]  += w*a0.w;
            T[4] += w*a1.x; T[5] += w*a1.y; T[6]  += w*a1.z; T[7]  += w*a1.w;
            T[8] += w*a2.x; T[9] += w*a2.y; T[10] += w*a2.z; T[11] += w*a2.w;
        }
        verts[o+0] = T[0]*x + T[1]*y + T[2]*z  + T[3];
        verts[o+1] = T[4]*x + T[5]*y + T[6]*z  + T[7];
        verts[o+2] = T[8]*x + T[9]*y + T[10]*z + T[11];
    }
}

extern "C" void kernel_launch(void* const* d_in, const int* in_sizes, int n_in,
                              void* d_out, int out_size, void* d_ws, size_t ws_size,
                              hipStream_t stream)
{
    const float* betas      = (const float*)d_in[0];
    const float* pose       = (const float*)d_in[1];
    const float* v_template = (const float*)d_in[2];
    const float* shapedirs  = (const float*)d_in[3];
    const float* posedirs   = (const float*)d_in[4];
    const float* Jreg       = (const float*)d_in[5];
    const float* lbs        = (const float*)d_in[6];

    float* ws   = (float*)d_ws;
    float* PF   = ws + WS_PF;
    float* A    = ws + WS_A;
    float* EXT  = ws + WS_EXT;
    float* JS   = ws + WS_JS;
    float* Jt0  = ws + WS_JT0;
    float* part = ws + WS_PART;

    float* verts = (float*)d_out;
    float* outJ  = verts + (size_t)B_N*V_N*3;

    hipLaunchKernelGGL(k_jreg, dim3(24,4), dim3(256), 0, stream, Jreg, v_template, shapedirs, part);
    hipLaunchKernelGGL(k_ext, dim3((NCOL+255)/256), dim3(256), 0, stream, shapedirs, v_template, EXT);
    hipLaunchKernelGGL(k_jred, dim3(24), dim3(64), 0, stream, part, JS, Jt0);
    hipLaunchKernelGGL(k_batch, dim3(256), dim3(64), 0, stream, pose, betas, JS, Jt0, PF, A, outJ);
    hipLaunchKernelGGL(k_gemm, dim3((V_N+63)/64, 16), dim3(256), 0, stream, posedirs, EXT, PF, verts);
    hipLaunchKernelGGL(k_skin, dim3((V_N+63)/64, 16), dim3(256), 0, stream, A, lbs, verts);
}

// Round 5
// 196.985 us; speedup vs baseline: 29.6818x; 1.0422x over previous
//
#include <hip/hip_runtime.h>
#include <math.h>

#define B_N 256
#define V_N 6890
#define J_N 24
#define KPF 207
#define KE  218
#define NCOL (V_N*3)   // 20670

__device__ __constant__ int c_par[24] = {-1,0,0,0,1,2,3,4,5,6,7,8,9,9,9,12,13,14,16,17,18,19,20,21};

// ws layout (floats)
#define WS_PF   0
#define WS_A    (WS_PF + B_N*KE)                 // 55808
#define WS_EXT  (WS_A + B_N*J_N*12)              // 129536
#define WS_PART (WS_EXT + 11*NCOL)               // 356906 (96*33 = 3168)

// ---------------- stage 0a: partial joint-regressor contraction ----------------
// part[(j,c)][0..29] = sum_v Jreg[j,v]*shapedirs[v,:,:], [30..32] = sum Jreg[j,v]*vt[v,:]
__global__ __launch_bounds__(256) void k_jreg(const float* __restrict__ Jreg,
        const float* __restrict__ vt, const float* __restrict__ sd,
        float* __restrict__ part)
{
    int j = blockIdx.x;
    int c = blockIdx.y;
    int tid = threadIdx.x;
    int v0 = c * 1723;
    int v1 = v0 + 1723; if (v1 > V_N) v1 = V_N;

    float acc[33];
    #pragma unroll
    for (int i = 0; i < 33; ++i) acc[i] = 0.f;

    for (int v = v0 + tid; v < v1; v += 256) {
        float r = Jreg[j*V_N + v];
        const float* s = sd + v*30;
        #pragma unroll
        for (int i = 0; i < 30; ++i) acc[i] += r * s[i];
        #pragma unroll
        for (int k = 0; k < 3; ++k) acc[30+k] += r * vt[v*3+k];
    }
    #pragma unroll
    for (int i = 0; i < 33; ++i) {
        #pragma unroll
        for (int off = 32; off > 0; off >>= 1)
            acc[i] += __shfl_down(acc[i], off, 64);
    }
    __shared__ float red[4][33];
    int wave = tid >> 6, lane = tid & 63;
    if (lane == 0) {
        #pragma unroll
        for (int i = 0; i < 33; ++i) red[wave][i] = acc[i];
    }
    __syncthreads();
    if (tid < 33) {
        float s = red[0][tid] + red[1][tid] + red[2][tid] + red[3][tid];
        part[(j*4 + c)*33 + tid] = s;
    }
}

// ---------------- stage 0b: build extended "posedirs" rows 207..217 ----------------
__global__ __launch_bounds__(256) void k_ext(const float* __restrict__ sd,
        const float* __restrict__ vt, float* __restrict__ EXT)
{
    int idx = blockIdx.x*256 + threadIdx.x;
    if (idx >= NCOL) return;
    int v = idx / 3, k = idx - v*3;
    #pragma unroll
    for (int l = 0; l < 10; ++l) EXT[l*NCOL + idx] = sd[v*30 + k*10 + l];
    EXT[10*NCOL + idx] = vt[idx];
}

// ---------------- stage 1: per-batch Rodrigues + kinematic chain (+ folded jred) ----------------
__global__ __launch_bounds__(64) void k_batch(const float* __restrict__ pose,
        const float* __restrict__ betas, const float* __restrict__ part,
        float* __restrict__ PF, float* __restrict__ A, float* __restrict__ outJ)
{
    int b = blockIdx.x;
    int lane = threadIdx.x;
    __shared__ float sR[24][9];
    __shared__ float sJ[24][3];
    __shared__ float sG[24][12];

    if (lane < 24) {
        float R[9];
        if (lane < 22) {
            float p0 = pose[b*72 + lane*3 + 0];
            float p1 = pose[b*72 + lane*3 + 1];
            float p2 = pose[b*72 + lane*3 + 2];
            float a0 = p0 + 1e-8f, a1 = p1 + 1e-8f, a2 = p2 + 1e-8f;
            float angle = sqrtf(a0*a0 + a1*a1 + a2*a2);
            float inv = 1.f / angle;
            float rx = p0*inv, ry = p1*inv, rz = p2*inv;
            float cc = cosf(angle), ss = sinf(angle), ic = 1.f - cc;
            R[0] = 1.f - ic*(ry*ry + rz*rz);
            R[1] = -ss*rz + ic*rx*ry;
            R[2] =  ss*ry + ic*rx*rz;
            R[3] =  ss*rz + ic*rx*ry;
            R[4] = 1.f - ic*(rx*rx + rz*rz);
            R[5] = -ss*rx + ic*ry*rz;
            R[6] = -ss*ry + ic*rx*rz;
            R[7] =  ss*rx + ic*ry*rz;
            R[8] = 1.f - ic*(rx*rx + ry*ry);
        } else {
            R[0]=1.f;R[1]=0.f;R[2]=0.f;R[3]=0.f;R[4]=1.f;R[5]=0.f;R[6]=0.f;R[7]=0.f;R[8]=1.f;
        }
        #pragma unroll
        for (int e = 0; e < 9; ++e) sR[lane][e] = R[e];
    }
    __syncthreads();
    // joints: sJ[j][k] = Jt0 + sum_l betas[l]*JS[j,k,l], summing part's 4 chunks inline
    for (int idx = lane; idx < 72; idx += 64) {
        int j = idx / 3, k = idx - j*3;
        const float* p0 = part + (j*4 + 0)*33;
        const float* p1 = part + (j*4 + 1)*33;
        const float* p2 = part + (j*4 + 2)*33;
        const float* p3 = part + (j*4 + 3)*33;
        float s = p0[30+k] + p1[30+k] + p2[30+k] + p3[30+k];
        #pragma unroll
        for (int l = 0; l < 10; ++l) {
            float js = p0[k*10+l] + p1[k*10+l] + p2[k*10+l] + p3[k*10+l];
            s += betas[b*10+l] * js;
        }
        sJ[j][k] = s;
    }
    __syncthreads();
    // PF rows 0..206 = pose_feature; 207..216 = betas; 217 = 1.0
    for (int idx = lane; idx < KPF; idx += 64) {
        int jj = 1 + idx/9, e = idx - (idx/9)*9;
        float id = (e==0 || e==4 || e==8) ? 1.f : 0.f;
        PF[b*KE + idx] = sR[jj][e] - id;
    }
    if (lane < 10) PF[b*KE + KPF + lane] = betas[b*10 + lane];
    if (lane == 0) PF[b*KE + 217] = 1.f;

    if (lane == 0) {
        #pragma unroll
        for (int r = 0; r < 3; ++r) {
            sG[0][r*4+0] = sR[0][r*3+0];
            sG[0][r*4+1] = sR[0][r*3+1];
            sG[0][r*4+2] = sR[0][r*3+2];
            sG[0][r*4+3] = sJ[0][r];
        }
        for (int i = 1; i < 24; ++i) {
            int p = c_par[i];
            float rel0 = sJ[i][0]-sJ[p][0], rel1 = sJ[i][1]-sJ[p][1], rel2 = sJ[i][2]-sJ[p][2];
            for (int r = 0; r < 3; ++r) {
                float g0 = sG[p][r*4+0], g1 = sG[p][r*4+1], g2 = sG[p][r*4+2], g3 = sG[p][r*4+3];
                sG[i][r*4+0] = g0*sR[i][0] + g1*sR[i][3] + g2*sR[i][6];
                sG[i][r*4+1] = g0*sR[i][1] + g1*sR[i][4] + g2*sR[i][7];
                sG[i][r*4+2] = g0*sR[i][2] + g1*sR[i][5] + g2*sR[i][8];
                sG[i][r*4+3] = g0*rel0 + g1*rel1 + g2*rel2 + g3;
            }
        }
    }
    __syncthreads();
    if (lane < 24) {
        int i = lane;
        #pragma unroll
        for (int r = 0; r < 3; ++r) {
            float g0 = sG[i][r*4+0], g1 = sG[i][r*4+1], g2 = sG[i][r*4+2], g3 = sG[i][r*4+3];
            outJ[b*72 + i*3 + r] = g3;
            float t = g3 - (g0*sJ[i][0] + g1*sJ[i][1] + g2*sJ[i][2]);
            A[(b*24+i)*12 + r*4+0] = g0;
            A[(b*24+i)*12 + r*4+1] = g1;
            A[(b*24+i)*12 + r*4+2] = g2;
            A[(b*24+i)*12 + r*4+3] = t;
        }
    }
}

// ---------------- stage 2: fused v_posed GEMM + skinning ----------------
// block = 256 thr (4 waves). Tile: 64 verts x 16 batches; thread = (vert=lane, 4 batches).
// Staging: thread owns row rr=tid>>4, f2-cols (tid&15)+16i, i<6 -> division-free,
// float2 global loads (rows are 8B-aligned) -> regs (issued before compute) -> ds_write_b64.
__global__ __launch_bounds__(256, 4) void k_fused(
        const float* __restrict__ posedirs, const float* __restrict__ EXT,
        const float* __restrict__ PF, const float* __restrict__ A,
        const float* __restrict__ W, float* __restrict__ out)
{
    constexpr int KT = 16;
    constexpr int NT = (KE + KT - 1) / KT;          // 14 (last tile 10 rows)
    __shared__ __align__(16) float sPD[2*KT*192];   // 24576 B (reused as sA in epilogue)
    __shared__ __align__(16) float sPFt[KE][16];    // 13952 B

    int tid  = threadIdx.x;
    int wave = tid >> 6, lane = tid & 63;
    int v0 = blockIdx.x * 64;
    int b0 = blockIdx.y * 16;
    int v  = v0 + lane;
    int lane3 = lane*3;

    // staging ownership
    int rr = tid >> 4;          // row within tile, 0..15
    int c2 = tid & 15;          // float2-column base
    // per-i byte offsets within a row (clamped in-range for ragged last vert-tile)
    int goffs[6];
    int loffs[6];
    #pragma unroll
    for (int i = 0; i < 6; ++i) {
        int col = v0*3 + (c2 + 16*i)*2;                       // float col in full row
        goffs[i] = (col + 2 <= NCOL) ? col*4 : (v0*3)*4;      // clamp to tile start
        loffs[i] = rr*192 + (c2 + 16*i)*2;                    // LDS float offset
    }

    // stage PF^T (one-time)
    #pragma unroll 1
    for (int idx = tid; idx < 16*KE; idx += 256) {
        int bl = idx & 15, r = idx >> 4;
        sPFt[r][bl] = PF[(b0+bl)*KE + r];
    }

    // prologue: stage tile 0 (rows 0..15, all < KPF) into buf 0
    {
        const char* srow = (const char*)(posedirs + (size_t)rr*NCOL);
        #pragma unroll
        for (int i = 0; i < 6; ++i) {
            float2 x = *reinterpret_cast<const float2*>(srow + goffs[i]);
            *reinterpret_cast<float2*>(&sPD[loffs[i]]) = x;
        }
    }
    __syncthreads();

    float acc[4][3];
    #pragma unroll
    for (int k = 0; k < 4; ++k) { acc[k][0]=0.f; acc[k][1]=0.f; acc[k][2]=0.f; }

    int cur = 0;
    #pragma unroll 1
    for (int t = 0; t < NT; ++t) {
        int rt = t * KT;
        int rows = KE - rt; if (rows > KT) rows = KT;

        // issue next tile's loads into registers (latency hides under compute)
        float2 nx[6];
        bool hav = false;
        if (t + 1 < NT) {
            int r = rt + KT + rr;
            if (r < KE) {
                const char* srow = (r < KPF)
                    ? (const char*)(posedirs + (size_t)r*NCOL)
                    : (const char*)(EXT + (size_t)(r-KPF)*NCOL);
                #pragma unroll
                for (int i = 0; i < 6; ++i)
                    nx[i] = *reinterpret_cast<const float2*>(srow + goffs[i]);
                hav = true;
            }
        }

        // compute current tile
        const float* buf = sPD + cur*(KT*192);
        #pragma unroll 4
        for (int q = 0; q < rows; ++q) {
            const float4 p4 = *reinterpret_cast<const float4*>(&sPFt[rt+q][wave*4]);
            const float* c3 = buf + q*192 + lane3;
            float x = c3[0], y = c3[1], z = c3[2];
            acc[0][0] += p4.x*x; acc[0][1] += p4.x*y; acc[0][2] += p4.x*z;
            acc[1][0] += p4.y*x; acc[1][1] += p4.y*y; acc[1][2] += p4.y*z;
            acc[2][0] += p4.z*x; acc[2][1] += p4.z*y; acc[2][2] += p4.z*z;
            acc[3][0] += p4.w*x; acc[3][1] += p4.w*y; acc[3][2] += p4.w*z;
        }

        // write staged registers into the other buffer (nobody reads it this iter)
        if (hav) {
            float* dst = sPD + (cur^1)*(KT*192);
            #pragma unroll
            for (int i = 0; i < 6; ++i)
                *reinterpret_cast<float2*>(&dst[loffs[i]]) = nx[i];
        }
        __syncthreads();
        cur ^= 1;
    }

    // ---- epilogue: skinning. Stage A (16 batches x 288 floats) into reused sPD ----
    {
        const float* Ag = A + (size_t)b0*288;
        #pragma unroll 1
        for (int idx = tid; idx < 16*288; idx += 256)
            sPD[idx] = Ag[idx];
    }
    __syncthreads();

    // per-vertex weights straight from global (16B-aligned rows; clamped index)
    int vc = (v < V_N) ? v : (V_N - 1);
    const float4* W4 = reinterpret_cast<const float4*>(W + (size_t)vc*24);
    float4 w0 = W4[0], w1 = W4[1], w2 = W4[2], w3 = W4[3], w4 = W4[4], w5 = W4[5];
    float wv[24] = {w0.x,w0.y,w0.z,w0.w, w1.x,w1.y,w1.z,w1.w, w2.x,w2.y,w2.z,w2.w,
                    w3.x,w3.y,w3.z,w3.w, w4.x,w4.y,w4.z,w4.w, w5.x,w5.y,w5.z,w5.w};

    #pragma unroll 1
    for (int k = 0; k < 4; ++k) {
        int bb = wave*4 + k;
        const float* Ab = sPD + bb*288;
        float T[12];
        #pragma unroll
        for (int e = 0; e < 12; ++e) T[e] = 0.f;
        #pragma unroll
        for (int j = 0; j < 24; ++j) {
            float w = wv[j];
            float4 a0 = *reinterpret_cast<const float4*>(Ab + j*12 + 0);
            float4 a1 = *reinterpret_cast<const float4*>(Ab + j*12 + 4);
            float4 a2 = *reinterpret_cast<const float4*>(Ab + j*12 + 8);
            T[0] += w*a0.x; T[1] += w*a0.y; T[2]  += w*a0.z; T[3]  += w*a0.w;
            T[4] += w*a1.x; T[5] += w*a1.y; T[6]  += w*a1.z; T[7]  += w*a1.w;
            T[8] += w*a2.x; T[9] += w*a2.y; T[10] += w*a2.z; T[11] += w*a2.w;
        }
        if (v < V_N) {
            float x = acc[k][0], y = acc[k][1], z = acc[k][2];
            size_t o = (size_t)(b0 + bb)*NCOL + (size_t)v*3;
            out[o+0] = T[0]*x + T[1]*y + T[2]*z  + T[3];
            out[o+1] = T[4]*x + T[5]*y + T[6]*z  + T[7];
            out[o+2] = T[8]*x + T[9]*y + T[10]*z + T[11];
        }
    }
}

extern "C" void kernel_launch(void* const* d_in, const int* in_sizes, int n_in,
                              void* d_out, int out_size, void* d_ws, size_t ws_size,
                              hipStream_t stream)
{
    const float* betas      = (const float*)d_in[0];
    const float* pose       = (const float*)d_in[1];
    const float* v_template = (const float*)d_in[2];
    const float* shapedirs  = (const float*)d_in[3];
    const float* posedirs   = (const float*)d_in[4];
    const float* Jreg       = (const float*)d_in[5];
    const float* lbs        = (const float*)d_in[6];

    float* ws   = (float*)d_ws;
    float* PF   = ws + WS_PF;
    float* A    = ws + WS_A;
    float* EXT  = ws + WS_EXT;
    float* part = ws + WS_PART;

    float* verts = (float*)d_out;
    float* outJ  = verts + (size_t)B_N*V_N*3;

    hipLaunchKernelGGL(k_jreg, dim3(24,4), dim3(256), 0, stream, Jreg, v_template, shapedirs, part);
    hipLaunchKernelGGL(k_ext, dim3((NCOL+255)/256), dim3(256), 0, stream, shapedirs, v_template, EXT);
    hipLaunchKernelGGL(k_batch, dim3(256), dim3(64), 0, stream, pose, betas, part, PF, A, outJ);
    hipLaunchKernelGGL(k_fused, dim3((V_N+63)/64, 16), dim3(256), 0, stream, posedirs, EXT, PF, A, lbs, verts);
}

// Round 6
// 118.469 us; speedup vs baseline: 49.3536x; 1.6628x over previous
//
#include <hip/hip_runtime.h>
#include <math.h>

#define B_N 256
#define V_N 6890
#define J_N 24
#define KPF 207
#define KE  218
#define NCOL (V_N*3)   // 20670

__device__ __constant__ int c_par[24] = {-1,0,0,0,1,2,3,4,5,6,7,8,9,9,9,12,13,14,16,17,18,19,20,21};

// ws layout (floats)
#define WS_PF   0
#define WS_A    (WS_PF + B_N*KE)                 // 55808 (PF stored transposed [KE][B_N])
#define WS_EXT  (WS_A + B_N*J_N*12)              // 129536
#define WS_PART (WS_EXT + 11*NCOL)               // 356906 (96*33 = 3168)

// ---------------- stage 0a: partial joint-regressor contraction ----------------
__global__ __launch_bounds__(256) void k_jreg(const float* __restrict__ Jreg,
        const float* __restrict__ vt, const float* __restrict__ sd,
        float* __restrict__ part)
{
    int j = blockIdx.x;
    int c = blockIdx.y;
    int tid = threadIdx.x;
    int v0 = c * 1723;
    int v1 = v0 + 1723; if (v1 > V_N) v1 = V_N;

    float acc[33];
    #pragma unroll
    for (int i = 0; i < 33; ++i) acc[i] = 0.f;

    for (int v = v0 + tid; v < v1; v += 256) {
        float r = Jreg[j*V_N + v];
        const float* s = sd + v*30;
        #pragma unroll
        for (int i = 0; i < 30; ++i) acc[i] += r * s[i];
        #pragma unroll
        for (int k = 0; k < 3; ++k) acc[30+k] += r * vt[v*3+k];
    }
    #pragma unroll
    for (int i = 0; i < 33; ++i) {
        #pragma unroll
        for (int off = 32; off > 0; off >>= 1)
            acc[i] += __shfl_down(acc[i], off, 64);
    }
    __shared__ float red[4][33];
    int wave = tid >> 6, lane = tid & 63;
    if (lane == 0) {
        #pragma unroll
        for (int i = 0; i < 33; ++i) red[wave][i] = acc[i];
    }
    __syncthreads();
    if (tid < 33) {
        float s = red[0][tid] + red[1][tid] + red[2][tid] + red[3][tid];
        part[(j*4 + c)*33 + tid] = s;
    }
}

// ---------------- stage 0b: build extended "posedirs" rows 207..217 ----------------
__global__ __launch_bounds__(256) void k_ext(const float* __restrict__ sd,
        const float* __restrict__ vt, float* __restrict__ EXT)
{
    int idx = blockIdx.x*256 + threadIdx.x;
    if (idx >= NCOL) return;
    int v = idx / 3, k = idx - v*3;
    #pragma unroll
    for (int l = 0; l < 10; ++l) EXT[l*NCOL + idx] = sd[v*30 + k*10 + l];
    EXT[10*NCOL + idx] = vt[idx];
}

// ---------------- stage 1: per-batch Rodrigues + kinematic chain (+ folded jred) ----------------
// PF is written TRANSPOSED: PFt[r*B_N + b]
__global__ __launch_bounds__(64) void k_batch(const float* __restrict__ pose,
        const float* __restrict__ betas, const float* __restrict__ part,
        float* __restrict__ PFt, float* __restrict__ A, float* __restrict__ outJ)
{
    int b = blockIdx.x;
    int lane = threadIdx.x;
    __shared__ float sR[24][9];
    __shared__ float sJ[24][3];
    __shared__ float sG[24][12];

    if (lane < 24) {
        float R[9];
        if (lane < 22) {
            float p0 = pose[b*72 + lane*3 + 0];
            float p1 = pose[b*72 + lane*3 + 1];
            float p2 = pose[b*72 + lane*3 + 2];
            float a0 = p0 + 1e-8f, a1 = p1 + 1e-8f, a2 = p2 + 1e-8f;
            float angle = sqrtf(a0*a0 + a1*a1 + a2*a2);
            float inv = 1.f / angle;
            float rx = p0*inv, ry = p1*inv, rz = p2*inv;
            float cc = cosf(angle), ss = sinf(angle), ic = 1.f - cc;
            R[0] = 1.f - ic*(ry*ry + rz*rz);
            R[1] = -ss*rz + ic*rx*ry;
            R[2] =  ss*ry + ic*rx*rz;
            R[3] =  ss*rz + ic*rx*ry;
            R[4] = 1.f - ic*(rx*rx + rz*rz);
            R[5] = -ss*rx + ic*ry*rz;
            R[6] = -ss*ry + ic*rx*rz;
            R[7] =  ss*rx + ic*ry*rz;
            R[8] = 1.f - ic*(rx*rx + ry*ry);
        } else {
            R[0]=1.f;R[1]=0.f;R[2]=0.f;R[3]=0.f;R[4]=1.f;R[5]=0.f;R[6]=0.f;R[7]=0.f;R[8]=1.f;
        }
        #pragma unroll
        for (int e = 0; e < 9; ++e) sR[lane][e] = R[e];
    }
    __syncthreads();
    for (int idx = lane; idx < 72; idx += 64) {
        int j = idx / 3, k = idx - j*3;
        const float* p0 = part + (j*4 + 0)*33;
        const float* p1 = part + (j*4 + 1)*33;
        const float* p2 = part + (j*4 + 2)*33;
        const float* p3 = part + (j*4 + 3)*33;
        float s = p0[30+k] + p1[30+k] + p2[30+k] + p3[30+k];
        #pragma unroll
        for (int l = 0; l < 10; ++l) {
            float js = p0[k*10+l] + p1[k*10+l] + p2[k*10+l] + p3[k*10+l];
            s += betas[b*10+l] * js;
        }
        sJ[j][k] = s;
    }
    __syncthreads();
    for (int idx = lane; idx < KPF; idx += 64) {
        int jj = 1 + idx/9, e = idx - (idx/9)*9;
        float id = (e==0 || e==4 || e==8) ? 1.f : 0.f;
        PFt[idx*B_N + b] = sR[jj][e] - id;
    }
    if (lane < 10) PFt[(KPF+lane)*B_N + b] = betas[b*10 + lane];
    if (lane == 0) PFt[217*B_N + b] = 1.f;

    if (lane == 0) {
        #pragma unroll
        for (int r = 0; r < 3; ++r) {
            sG[0][r*4+0] = sR[0][r*3+0];
            sG[0][r*4+1] = sR[0][r*3+1];
            sG[0][r*4+2] = sR[0][r*3+2];
            sG[0][r*4+3] = sJ[0][r];
        }
        for (int i = 1; i < 24; ++i) {
            int p = c_par[i];
            float rel0 = sJ[i][0]-sJ[p][0], rel1 = sJ[i][1]-sJ[p][1], rel2 = sJ[i][2]-sJ[p][2];
            for (int r = 0; r < 3; ++r) {
                float g0 = sG[p][r*4+0], g1 = sG[p][r*4+1], g2 = sG[p][r*4+2], g3 = sG[p][r*4+3];
                sG[i][r*4+0] = g0*sR[i][0] + g1*sR[i][3] + g2*sR[i][6];
                sG[i][r*4+1] = g0*sR[i][1] + g1*sR[i][4] + g2*sR[i][7];
                sG[i][r*4+2] = g0*sR[i][2] + g1*sR[i][5] + g2*sR[i][8];
                sG[i][r*4+3] = g0*rel0 + g1*rel1 + g2*rel2 + g3;
            }
        }
    }
    __syncthreads();
    if (lane < 24) {
        int i = lane;
        #pragma unroll
        for (int r = 0; r < 3; ++r) {
            float g0 = sG[i][r*4+0], g1 = sG[i][r*4+1], g2 = sG[i][r*4+2], g3 = sG[i][r*4+3];
            outJ[b*72 + i*3 + r] = g3;
            float t = g3 - (g0*sJ[i][0] + g1*sJ[i][1] + g2*sJ[i][2]);
            A[(b*24+i)*12 + r*4+0] = g0;
            A[(b*24+i)*12 + r*4+1] = g1;
            A[(b*24+i)*12 + r*4+2] = g2;
            A[(b*24+i)*12 + r*4+3] = t;
        }
    }
}

// ---------------- stage 2: fused v_posed GEMM + skinning ----------------
// 1-D grid of 864 blocks, XCD-swizzled: c=bid&7, j=bid>>3, w=c*108+j; vt=w>>3, bt=w&7.
// All 8 batch-tiles of a vert-slice land on one XCD -> posedirs slice fetched ~once.
// Tile: 64 verts x 32 batches; thread = (vert=lane, 8 batches = wave*8+k).
__global__ __launch_bounds__(256, 3) void k_fused(
        const float* __restrict__ posedirs, const float* __restrict__ EXT,
        const float* __restrict__ PFt, const float* __restrict__ A,
        const float* __restrict__ W, float* __restrict__ out)
{
    constexpr int KT = 16;
    constexpr int NT = (KE + KT - 1) / KT;          // 14 (last tile 10 rows)
    constexpr int BT = 32;
    // partitioned shared: sPD 2*16*192 = 6144 | sPFt 218*32 = 6976  (total 52480 B)
    __shared__ __align__(16) float smem[2*KT*192 + KE*BT];
    float* sPD  = smem;
    float* sPFt = smem + 2*KT*192;

    int tid  = threadIdx.x;
    int wave = tid >> 6, lane = tid & 63;

    int bid = blockIdx.x;
    int w   = (bid & 7)*108 + (bid >> 3);
    int vt  = w >> 3, bt = w & 7;
    int v0 = vt * 64;
    int b0 = bt * BT;
    int v  = v0 + lane;
    int lane3 = lane*3;

    // staging ownership: row rr = tid>>4, float2-cols (tid&15)+16i
    int rr = tid >> 4;
    int c2 = tid & 15;
    int goffs[6];
    int loffs[6];
    #pragma unroll
    for (int i = 0; i < 6; ++i) {
        int col = v0*3 + (c2 + 16*i)*2;
        goffs[i] = (col + 2 <= NCOL) ? col*4 : (v0*3)*4;      // clamp in-tile
        loffs[i] = rr*192 + (c2 + 16*i)*2;
    }

    // stage PF^T (one-time, coalesced: PFt is [KE][256])
    #pragma unroll 1
    for (int idx = tid; idx < KE*BT; idx += 256) {
        int r = idx >> 5, bl = idx & 31;
        sPFt[r*BT + bl] = PFt[r*B_N + b0 + bl];
    }

    // prologue: stage tile 0 (rows 0..15, all < KPF) into buf 0
    {
        const char* srow = (const char*)(posedirs + (size_t)rr*NCOL);
        #pragma unroll
        for (int i = 0; i < 6; ++i) {
            float2 x = *reinterpret_cast<const float2*>(srow + goffs[i]);
            *reinterpret_cast<float2*>(&sPD[loffs[i]]) = x;
        }
    }
    __syncthreads();

    float acc[8][3];
    #pragma unroll
    for (int k = 0; k < 8; ++k) { acc[k][0]=0.f; acc[k][1]=0.f; acc[k][2]=0.f; }

    int cur = 0;
    #pragma unroll 1
    for (int t = 0; t < NT; ++t) {
        int rt = t * KT;
        int rows = KE - rt; if (rows > KT) rows = KT;

        // issue next tile's loads into registers (hide latency under compute)
        float2 nx[6];
        bool hav = false;
        if (t + 1 < NT) {
            int r = rt + KT + rr;
            if (r < KE) {
                const char* srow = (r < KPF)
                    ? (const char*)(posedirs + (size_t)r*NCOL)
                    : (const char*)(EXT + (size_t)(r-KPF)*NCOL);
                #pragma unroll
                for (int i = 0; i < 6; ++i)
                    nx[i] = *reinterpret_cast<const float2*>(srow + goffs[i]);
                hav = true;
            }
        }

        // compute current tile: per row 1 ds_read_b96 + 2 broadcast b128 + 24 fmac
        const float* buf = sPD + cur*(KT*192);
        #pragma unroll 4
        for (int q = 0; q < rows; ++q) {
            const float4 pa = *reinterpret_cast<const float4*>(&sPFt[(rt+q)*BT + wave*8]);
            const float4 pb = *reinterpret_cast<const float4*>(&sPFt[(rt+q)*BT + wave*8 + 4]);
            const float* c3 = buf + q*192 + lane3;
            float x = c3[0], y = c3[1], z = c3[2];
            acc[0][0] += pa.x*x; acc[0][1] += pa.x*y; acc[0][2] += pa.x*z;
            acc[1][0] += pa.y*x; acc[1][1] += pa.y*y; acc[1][2] += pa.y*z;
            acc[2][0] += pa.z*x; acc[2][1] += pa.z*y; acc[2][2] += pa.z*z;
            acc[3][0] += pa.w*x; acc[3][1] += pa.w*y; acc[3][2] += pa.w*z;
            acc[4][0] += pb.x*x; acc[4][1] += pb.x*y; acc[4][2] += pb.x*z;
            acc[5][0] += pb.y*x; acc[5][1] += pb.y*y; acc[5][2] += pb.y*z;
            acc[6][0] += pb.z*x; acc[6][1] += pb.z*y; acc[6][2] += pb.z*z;
            acc[7][0] += pb.w*x; acc[7][1] += pb.w*y; acc[7][2] += pb.w*z;
        }

        // write prefetched registers into the other buffer
        if (hav) {
            float* dst = sPD + (cur^1)*(KT*192);
            #pragma unroll
            for (int i = 0; i < 6; ++i)
                *reinterpret_cast<float2*>(&dst[loffs[i]]) = nx[i];
        }
        __syncthreads();
        cur ^= 1;
    }

    // ---- epilogue: skinning. Stage A (32 batches x 288 floats = 9216) into reused smem ----
    {
        const float* Ag = A + (size_t)b0*288;
        #pragma unroll 1
        for (int idx = tid; idx < BT*288; idx += 256)
            smem[idx] = Ag[idx];
    }
    __syncthreads();

    // per-vertex weights from global (16B-aligned rows; clamped index, stores masked)
    int vc = (v < V_N) ? v : (V_N - 1);
    const float4* W4 = reinterpret_cast<const float4*>(W + (size_t)vc*24);
    float4 w0 = W4[0], w1 = W4[1], w2 = W4[2], w3 = W4[3], w4 = W4[4], w5 = W4[5];
    float wv[24] = {w0.x,w0.y,w0.z,w0.w, w1.x,w1.y,w1.z,w1.w, w2.x,w2.y,w2.z,w2.w,
                    w3.x,w3.y,w3.z,w3.w, w4.x,w4.y,w4.z,w4.w, w5.x,w5.y,w5.z,w5.w};

    #pragma unroll 1
    for (int k = 0; k < 8; ++k) {
        int bb = wave*8 + k;
        const float* Ab = smem + bb*288;
        float T[12];
        #pragma unroll
        for (int e = 0; e < 12; ++e) T[e] = 0.f;
        #pragma unroll
        for (int j = 0; j < 24; ++j) {
            float ww = wv[j];
            float4 a0 = *reinterpret_cast<const float4*>(Ab + j*12 + 0);
            float4 a1 = *reinterpret_cast<const float4*>(Ab + j*12 + 4);
            float4 a2 = *reinterpret_cast<const float4*>(Ab + j*12 + 8);
            T[0] += ww*a0.x; T[1] += ww*a0.y; T[2]  += ww*a0.z; T[3]  += ww*a0.w;
            T[4] += ww*a1.x; T[5] += ww*a1.y; T[6]  += ww*a1.z; T[7]  += ww*a1.w;
            T[8] += ww*a2.x; T[9] += ww*a2.y; T[10] += ww*a2.z; T[11] += ww*a2.w;
        }
        if (v < V_N) {
            float x = acc[k][0], y = acc[k][1], z = acc[k][2];
            size_t o = (size_t)(b0 + bb)*NCOL + (size_t)v*3;
            out[o+0] = T[0]*x + T[1]*y + T[2]*z  + T[3];
            out[o+1] = T[4]*x + T[5]*y + T[6]*z  + T[7];
            out[o+2] = T[8]*x + T[9]*y + T[10]*z + T[11];
        }
    }
}

extern "C" void kernel_launch(void* const* d_in, const int* in_sizes, int n_in,
                              void* d_out, int out_size, void* d_ws, size_t ws_size,
                              hipStream_t stream)
{
    const float* betas      = (const float*)d_in[0];
    const float* pose       = (const float*)d_in[1];
    const float* v_template = (const float*)d_in[2];
    const float* shapedirs  = (const float*)d_in[3];
    const float* posedirs   = (const float*)d_in[4];
    const float* Jreg       = (const float*)d_in[5];
    const float* lbs        = (const float*)d_in[6];

    float* ws   = (float*)d_ws;
    float* PFt  = ws + WS_PF;
    float* A    = ws + WS_A;
    float* EXT  = ws + WS_EXT;
    float* part = ws + WS_PART;

    float* verts = (float*)d_out;
    float* outJ  = verts + (size_t)B_N*V_N*3;

    hipLaunchKernelGGL(k_jreg, dim3(24,4), dim3(256), 0, stream, Jreg, v_template, shapedirs, part);
    hipLaunchKernelGGL(k_ext, dim3((NCOL+255)/256), dim3(256), 0, stream, shapedirs, v_template, EXT);
    hipLaunchKernelGGL(k_batch, dim3(256), dim3(64), 0, stream, pose, betas, part, PFt, A, outJ);
    hipLaunchKernelGGL(k_fused, dim3(8*108), dim3(256), 0, stream, posedirs, EXT, PFt, A, lbs, verts);
}